// Round 9
// baseline (574.181 us; speedup 1.0000x reference)
//
#include <hip/hip_runtime.h>
#include <hip/hip_bf16.h>

typedef unsigned short u16;
typedef __bf16 bf16x8 __attribute__((ext_vector_type(8)));
typedef float f32x4 __attribute__((ext_vector_type(4)));

__device__ __forceinline__ u16 f2bf(float f) {
    unsigned u = __builtin_bit_cast(unsigned, f);
    unsigned r = (u + 0x7fffu + ((u >> 16) & 1u)) >> 16;
    return (u16)r;
}

#define GLDS16(g, l)                                                      \
    __builtin_amdgcn_global_load_lds(                                     \
        (const __attribute__((address_space(1))) void*)(g),               \
        (__attribute__((address_space(3))) void*)(l), 16, 0, 0)

// ---- fused prep ----
// blocks [0,3072): flat f32->bf16 convert of x (1048576 f4) + V0 (524288 f4).
// blocks [3072,4608): 64x64 transpose+convert tiles: V1 -> V1t, V2 -> V2t.
// block 0 additionally zeroes the 448 split-K tile counters.
__global__ __launch_bounds__(256) void prep(const float* __restrict__ x,
                                            u16* __restrict__ xb,
                                            const float* __restrict__ V0,
                                            u16* __restrict__ V0b,
                                            const float* __restrict__ V1,
                                            u16* __restrict__ V1t,
                                            const float* __restrict__ V2,
                                            u16* __restrict__ V2t,
                                            int* __restrict__ ctr) {
    __shared__ float tile[64][65];
    const int b = blockIdx.x, t = threadIdx.x;
    if (b < 3072) {
        if (b == 0)
            for (int i = t; i < 448; i += 256) ctr[i] = 0;
        int i0 = b * 512 + t;
#pragma unroll
        for (int p = 0; p < 2; ++p) {
            int i = i0 + p * 256;
            const float* s; u16* d; int j;
            if (i < 1048576) { s = x; d = xb; j = i; }
            else { s = V0; d = V0b; j = i - 1048576; }
            float4 v = ((const float4*)s)[j];
            ushort4 o; o.x = f2bf(v.x); o.y = f2bf(v.y); o.z = f2bf(v.z); o.w = f2bf(v.w);
            ((ushort4*)d)[j] = o;
        }
        return;
    }
    const int b2 = b - 3072;
    const float* src; u16* dst; int C, rt, ct;
    if (b2 < 1024) { src = V1; dst = V1t; C = 2048; rt = b2 >> 5; ct = b2 & 31; }
    else { int b3 = b2 - 1024; src = V2; dst = V2t; C = 1024; rt = b3 >> 4; ct = b3 & 15; }
    const int r0 = rt * 64, c0 = ct * 64;
    const int trow = t >> 4;       // 0..15
    const int tc4 = t & 15;        // float4 / ushort4 chunk index

#pragma unroll
    for (int p = 0; p < 4; ++p) {
        int r = p * 16 + trow;
        float4 v = *(const float4*)&src[(size_t)(r0 + r) * C + c0 + tc4 * 4];
        tile[r][tc4 * 4 + 0] = v.x; tile[r][tc4 * 4 + 1] = v.y;
        tile[r][tc4 * 4 + 2] = v.z; tile[r][tc4 * 4 + 3] = v.w;
    }
    __syncthreads();
#pragma unroll
    for (int p = 0; p < 4; ++p) {
        int c = p * 16 + trow;
        int rr = tc4 * 4;
        ushort4 o;
        o.x = f2bf(tile[rr + 0][c]); o.y = f2bf(tile[rr + 1][c]);
        o.z = f2bf(tile[rr + 2][c]); o.w = f2bf(tile[rr + 3][c]);
        *(ushort4*)&dst[(size_t)(c0 + c) * 2048 + r0 + rr] = o;
    }
}

// ---- bf16 GEMM with fused split-K reduction (last-arriving block reduces) ----
// 128x128 tile, BK=32, 8 waves (2x4), per-wave 64x32, double-buffered LDS,
// one vmcnt(0)+s_barrier per K-step. f32 partials; reduction is z-ordered ->
// deterministic output value regardless of block finish order.
template <int KS, int OUT_BF16>
__global__ __launch_bounds__(512) void gemm_fused(const u16* __restrict__ A,
                                                  const u16* __restrict__ Bt,
                                                  float* __restrict__ pf,
                                                  void* __restrict__ Cfinal,
                                                  int* __restrict__ ctr,
                                                  int M, int N, int Ktot, int Kc) {
    __shared__ u16 sA[2][128 * 32];
    __shared__ u16 sB[2][128 * 32];
    __shared__ int sLast;

    const int t = threadIdx.x;
    const int lane = t & 63;
    const int w = t >> 6;             // 0..7
    const int wr = w >> 2, wc = w & 3;
    const int l15 = lane & 15, l4 = lane >> 4;
    const int row0 = blockIdx.y * 128, col0 = blockIdx.x * 128;
    const int kbase = blockIdx.z * Kc;
    const size_t MN = (size_t)M * N;

    f32x4 acc[4][2] = {};

    const int sr = t >> 2;
    const int sk = (t & 3) * 8;
    const u16* Ab = A  + (size_t)(row0 + sr) * Ktot + kbase + sk;
    const u16* Bb = Bt + (size_t)(col0 + sr) * Ktot + kbase + sk;

    GLDS16(Ab, &sA[0][t * 8]);
    GLDS16(Bb, &sB[0][t * 8]);
    asm volatile("s_waitcnt vmcnt(0)" ::: "memory");
    __builtin_amdgcn_s_barrier();

    const int nK = Kc >> 5;
    int cur = 0;
    for (int kt = 0; kt < nK; ++kt) {
        if (kt + 1 < nK) {
            GLDS16(Ab + (kt + 1) * 32, &sA[cur ^ 1][t * 8]);
            GLDS16(Bb + (kt + 1) * 32, &sB[cur ^ 1][t * 8]);
        }

        bf16x8 af[4], bfr[2];
#pragma unroll
        for (int m = 0; m < 4; ++m)
            af[m] = *(const bf16x8*)&sA[cur][(wr * 64 + m * 16 + l15) * 32 + l4 * 8];
#pragma unroll
        for (int n = 0; n < 2; ++n)
            bfr[n] = *(const bf16x8*)&sB[cur][(wc * 32 + n * 16 + l15) * 32 + l4 * 8];
#pragma unroll
        for (int m = 0; m < 4; ++m)
#pragma unroll
            for (int n = 0; n < 2; ++n)
                acc[m][n] = __builtin_amdgcn_mfma_f32_16x16x32_bf16(af[m], bfr[n], acc[m][n], 0, 0, 0);

        asm volatile("s_waitcnt vmcnt(0)" ::: "memory");
        __builtin_amdgcn_s_barrier();
        cur ^= 1;
    }

    // write f32 partial for this z-slice (D row=(lane>>4)*4+j, col=lane&15)
    float* myp = pf + (size_t)blockIdx.z * MN;
#pragma unroll
    for (int m = 0; m < 4; ++m)
#pragma unroll
        for (int n = 0; n < 2; ++n) {
            int r = row0 + wr * 64 + m * 16 + l4 * 4;
            int c = col0 + wc * 32 + n * 16 + l15;
#pragma unroll
            for (int j = 0; j < 4; ++j)
                myp[(size_t)(r + j) * N + c] = acc[m][n][j];
        }

    // signal partial complete (release); last block acquires + reduces
    __threadfence();
    if (t == 0) {
        const int tileId = blockIdx.y * gridDim.x + blockIdx.x;
        int old = __hip_atomic_fetch_add(&ctr[tileId], 1, __ATOMIC_ACQ_REL,
                                         __HIP_MEMORY_SCOPE_AGENT);
        sLast = (old == KS - 1);
    }
    __syncthreads();
    if (!sLast) return;

    // reduce KS partials for this 128x128 tile (z-ordered sum -> deterministic)
#pragma unroll
    for (int q = 0; q < 8; ++q) {
        int f = t * 8 + q;                 // 0..4095 float4 chunks of the tile
        int row = f >> 5, c4 = f & 31;
        size_t addr = (size_t)(row0 + row) * N + col0 + c4 * 4;
        float4 s = *(const float4*)(pf + addr);
#pragma unroll
        for (int z = 1; z < KS; ++z) {
            float4 v = *(const float4*)(pf + z * MN + addr);
            s.x += v.x; s.y += v.y; s.z += v.z; s.w += v.w;
        }
        if (OUT_BF16) {
            ushort4 o; o.x = f2bf(s.x); o.y = f2bf(s.y); o.z = f2bf(s.z); o.w = f2bf(s.w);
            *(ushort4*)&((u16*)Cfinal)[addr] = o;
        } else {
            *(float4*)&((float*)Cfinal)[addr] = s;
        }
    }
}

// dims: x(4096,1024)  V0(1024,2048) V1(2048,2048) V2(2048,1024)
// out = x @ ((V0@V1)@V2):
//   P1  = V0@V1          (1024x2048 bf16), split-K 4x512, ctr[0..128)
//   P2t = V2^T @ P1^T    (1024x1024 bf16), split-K 8x256, ctr[128..192)
//   G   = x @ P2         (4096x1024 f32 -> d_out), split-K 2x512, ctr[192..448)
// d_in order: x, V0, W0, V1, W1, V2, W2
extern "C" void kernel_launch(void* const* d_in, const int* in_sizes, int n_in,
                              void* d_out, int out_size, void* d_ws, size_t ws_size,
                              hipStream_t stream) {
    const float* x  = (const float*)d_in[0];
    const float* V0 = (const float*)d_in[1];
    const float* V1 = (const float*)d_in[3];
    const float* V2 = (const float*)d_in[5];

    char* ws = (char*)d_ws;
    u16* xb   = (u16*)(ws);                          // 8 MB  (4096x1024)
    u16* V0b  = (u16*)(ws + ((size_t)8 << 20));      // 4 MB  (1024x2048)
    u16* V1t  = (u16*)(ws + ((size_t)12 << 20));     // 8 MB  (2048x2048 = V1^T)
    u16* V2t  = (u16*)(ws + ((size_t)20 << 20));     // 4 MB  (1024x2048 = V2^T)
    u16* P1   = (u16*)(ws + ((size_t)24 << 20));     // 4 MB  (1024x2048)
    u16* P2t  = (u16*)(ws + ((size_t)28 << 20));     // 2 MB  (1024x1024)
    int* ctr  = (int*)(ws + ((size_t)30 << 20));     // 4 KB  (448 counters)
    float* pf = (float*)(ws + ((size_t)32 << 20));   // 32 MB f32 split-K partials

    prep<<<4608, 256, 0, stream>>>(x, xb, V0, V0b, V1, V1t, V2, V2t, ctr);

    // P1 = V0 @ V1 : M=1024, N=2048, K=2048, split-K 4x512
    gemm_fused<4, 1><<<dim3(16, 8, 4), 512, 0, stream>>>(V0b, V1t, pf, P1, ctr,
                                                         1024, 2048, 2048, 512);
    // P2t = V2^T @ P1^T : M=1024, N=1024, K=2048, split-K 8x256
    gemm_fused<8, 1><<<dim3(8, 8, 8), 512, 0, stream>>>(V2t, P1, pf, P2t, ctr + 128,
                                                        1024, 1024, 2048, 256);
    // G = x @ P2 : M=4096, N=1024, K=1024, split-K 2x512
    gemm_fused<2, 0><<<dim3(8, 32, 2), 512, 0, stream>>>(xb, P2t, pf, d_out, ctr + 192,
                                                         4096, 1024, 1024, 512);
}

// Round 10
// 75.472 us; speedup vs baseline: 7.6079x; 7.6079x over previous
//
#include <hip/hip_runtime.h>
#include <hip/hip_bf16.h>

typedef unsigned short u16;
typedef __bf16 bf16x8 __attribute__((ext_vector_type(8)));
typedef float f32x4 __attribute__((ext_vector_type(4)));

__device__ __forceinline__ u16 f2bf(float f) {
    unsigned u = __builtin_bit_cast(unsigned, f);
    unsigned r = (u + 0x7fffu + ((u >> 16) & 1u)) >> 16;
    return (u16)r;
}

#define GLDS16(g, l)                                                      \
    __builtin_amdgcn_global_load_lds(                                     \
        (const __attribute__((address_space(1))) void*)(g),               \
        (__attribute__((address_space(3))) void*)(l), 16, 0, 0)

// ---- prep: convert V0 -> bf16; transpose+convert V1 -> V1t, V2 -> V2t ----
// blocks [0,1024): V0 flat convert (524288 f4, 2 f4/thread)
// blocks [1024,2560): one 64x64 transpose tile per block
__global__ __launch_bounds__(256) void prep(const float* __restrict__ V0,
                                            u16* __restrict__ V0b,
                                            const float* __restrict__ V1,
                                            u16* __restrict__ V1t,
                                            const float* __restrict__ V2,
                                            u16* __restrict__ V2t) {
    __shared__ float tile[64][65];
    const int b = blockIdx.x, t = threadIdx.x;
    if (b < 1024) {
        int i0 = b * 512 + t;
#pragma unroll
        for (int p = 0; p < 2; ++p) {
            int j = i0 + p * 256;
            float4 v = ((const float4*)V0)[j];
            ushort4 o; o.x = f2bf(v.x); o.y = f2bf(v.y); o.z = f2bf(v.z); o.w = f2bf(v.w);
            ((ushort4*)V0b)[j] = o;
        }
        return;
    }
    const int b2 = b - 1024;
    const float* src; u16* dst; int C, rt, ct;
    if (b2 < 1024) { src = V1; dst = V1t; C = 2048; rt = b2 >> 5; ct = b2 & 31; }
    else { int b3 = b2 - 1024; src = V2; dst = V2t; C = 1024; rt = b3 >> 4; ct = b3 & 15; }
    const int r0 = rt * 64, c0 = ct * 64;
    const int trow = t >> 4;       // 0..15
    const int tc4 = t & 15;        // float4 / ushort4 chunk index

#pragma unroll
    for (int p = 0; p < 4; ++p) {
        int r = p * 16 + trow;
        float4 v = *(const float4*)&src[(size_t)(r0 + r) * C + c0 + tc4 * 4];
        tile[r][tc4 * 4 + 0] = v.x; tile[r][tc4 * 4 + 1] = v.y;
        tile[r][tc4 * 4 + 2] = v.z; tile[r][tc4 * 4 + 3] = v.w;
    }
    __syncthreads();
#pragma unroll
    for (int p = 0; p < 4; ++p) {
        int c = p * 16 + trow;
        int rr = tc4 * 4;
        ushort4 o;
        o.x = f2bf(tile[rr + 0][c]); o.y = f2bf(tile[rr + 1][c]);
        o.z = f2bf(tile[rr + 2][c]); o.w = f2bf(tile[rr + 3][c]);
        *(ushort4*)&dst[(size_t)(c0 + c) * 2048 + r0 + rr] = o;
    }
}

// ---------------- bf16 GEMM: Cpart(z) = A(M x Kc slice) * Bt(N x Kc slice)^T --
// 128x128 tile, BK=32, 8 waves (2x4), per-wave 64x32, double-buffered LDS with
// one vmcnt(0)+s_barrier per K-step (stage t+1 issued before compute of t).
__global__ __launch_bounds__(512) void gemm_bt(const u16* __restrict__ A,
                                               const u16* __restrict__ Bt,
                                               u16* __restrict__ Cpart,
                                               int M, int N, int Ktot, int Kc) {
    __shared__ u16 sA[2][128 * 32];
    __shared__ u16 sB[2][128 * 32];

    const int t = threadIdx.x;
    const int lane = t & 63;
    const int w = t >> 6;             // 0..7
    const int wr = w >> 2, wc = w & 3;
    const int l15 = lane & 15, l4 = lane >> 4;
    const int row0 = blockIdx.y * 128, col0 = blockIdx.x * 128;
    const int kbase = blockIdx.z * Kc;

    f32x4 acc[4][2] = {};

    const int sr = t >> 2;
    const int sk = (t & 3) * 8;
    const u16* Ab = A  + (size_t)(row0 + sr) * Ktot + kbase + sk;
    const u16* Bb = Bt + (size_t)(col0 + sr) * Ktot + kbase + sk;

    GLDS16(Ab, &sA[0][t * 8]);
    GLDS16(Bb, &sB[0][t * 8]);
    asm volatile("s_waitcnt vmcnt(0)" ::: "memory");
    __builtin_amdgcn_s_barrier();

    const int nK = Kc >> 5;
    int cur = 0;
    for (int kt = 0; kt < nK; ++kt) {
        if (kt + 1 < nK) {
            GLDS16(Ab + (kt + 1) * 32, &sA[cur ^ 1][t * 8]);
            GLDS16(Bb + (kt + 1) * 32, &sB[cur ^ 1][t * 8]);
        }

        bf16x8 af[4], bfr[2];
#pragma unroll
        for (int m = 0; m < 4; ++m)
            af[m] = *(const bf16x8*)&sA[cur][(wr * 64 + m * 16 + l15) * 32 + l4 * 8];
#pragma unroll
        for (int n = 0; n < 2; ++n)
            bfr[n] = *(const bf16x8*)&sB[cur][(wc * 32 + n * 16 + l15) * 32 + l4 * 8];
#pragma unroll
        for (int m = 0; m < 4; ++m)
#pragma unroll
            for (int n = 0; n < 2; ++n)
                acc[m][n] = __builtin_amdgcn_mfma_f32_16x16x32_bf16(af[m], bfr[n], acc[m][n], 0, 0, 0);

        asm volatile("s_waitcnt vmcnt(0)" ::: "memory");
        __builtin_amdgcn_s_barrier();
        cur ^= 1;
    }

    const size_t zoff = (size_t)blockIdx.z * M * N;
#pragma unroll
    for (int m = 0; m < 4; ++m)
#pragma unroll
        for (int n = 0; n < 2; ++n) {
            int r = row0 + wr * 64 + m * 16 + l4 * 4;
            int c = col0 + wc * 32 + n * 16 + l15;
#pragma unroll
            for (int j = 0; j < 4; ++j)
                Cpart[zoff + (size_t)(r + j) * N + c] = f2bf(acc[m][n][j]);
        }
}

// ---- reduce1 (4 partials -> P1 bf16) + x f32->bf16 convert, fused ----
// blocks [0,1024): reduce P1 (mn = 1024*2048, 8 elems/thread)
// blocks [1024,3072): x convert (1048576 f4, 2 f4/thread)
__global__ __launch_bounds__(256) void reduce1_xconv(const u16* __restrict__ part,
                                                     u16* __restrict__ P1,
                                                     const float* __restrict__ x,
                                                     u16* __restrict__ xb) {
    const int b = blockIdx.x, t = threadIdx.x;
    if (b < 1024) {
        const int mn = 1024 * 2048;
        int i = b * 256 + t;
        float s[8] = {0, 0, 0, 0, 0, 0, 0, 0};
#pragma unroll
        for (int z = 0; z < 4; ++z) {
            uint4 v = ((const uint4*)(part + (size_t)z * mn))[i];
            unsigned a0 = v.x, a1 = v.y, a2 = v.z, a3 = v.w;
            s[0] += __builtin_bit_cast(float, a0 << 16);
            s[1] += __builtin_bit_cast(float, a0 & 0xffff0000u);
            s[2] += __builtin_bit_cast(float, a1 << 16);
            s[3] += __builtin_bit_cast(float, a1 & 0xffff0000u);
            s[4] += __builtin_bit_cast(float, a2 << 16);
            s[5] += __builtin_bit_cast(float, a2 & 0xffff0000u);
            s[6] += __builtin_bit_cast(float, a3 << 16);
            s[7] += __builtin_bit_cast(float, a3 & 0xffff0000u);
        }
        uint4 o;
        o.x = (unsigned)f2bf(s[0]) | ((unsigned)f2bf(s[1]) << 16);
        o.y = (unsigned)f2bf(s[2]) | ((unsigned)f2bf(s[3]) << 16);
        o.z = (unsigned)f2bf(s[4]) | ((unsigned)f2bf(s[5]) << 16);
        o.w = (unsigned)f2bf(s[6]) | ((unsigned)f2bf(s[7]) << 16);
        ((uint4*)P1)[i] = o;
        return;
    }
    int i0 = (b - 1024) * 512 + t;
#pragma unroll
    for (int p = 0; p < 2; ++p) {
        int j = i0 + p * 256;
        float4 v = ((const float4*)x)[j];
        ushort4 o; o.x = f2bf(v.x); o.y = f2bf(v.y); o.z = f2bf(v.z); o.w = f2bf(v.w);
        ((ushort4*)xb)[j] = o;
    }
}

// ---- reduce2: sum 8 bf16 partials -> P2t bf16 (8 elems/thread) ----
__global__ __launch_bounds__(256) void reduce2(const u16* __restrict__ part,
                                               u16* __restrict__ P2t) {
    const int mn = 1024 * 1024;
    int i = blockIdx.x * 256 + threadIdx.x;
    float s[8] = {0, 0, 0, 0, 0, 0, 0, 0};
#pragma unroll
    for (int z = 0; z < 8; ++z) {
        uint4 v = ((const uint4*)(part + (size_t)z * mn))[i];
        unsigned a0 = v.x, a1 = v.y, a2 = v.z, a3 = v.w;
        s[0] += __builtin_bit_cast(float, a0 << 16);
        s[1] += __builtin_bit_cast(float, a0 & 0xffff0000u);
        s[2] += __builtin_bit_cast(float, a1 << 16);
        s[3] += __builtin_bit_cast(float, a1 & 0xffff0000u);
        s[4] += __builtin_bit_cast(float, a2 << 16);
        s[5] += __builtin_bit_cast(float, a2 & 0xffff0000u);
        s[6] += __builtin_bit_cast(float, a3 << 16);
        s[7] += __builtin_bit_cast(float, a3 & 0xffff0000u);
    }
    uint4 o;
    o.x = (unsigned)f2bf(s[0]) | ((unsigned)f2bf(s[1]) << 16);
    o.y = (unsigned)f2bf(s[2]) | ((unsigned)f2bf(s[3]) << 16);
    o.z = (unsigned)f2bf(s[4]) | ((unsigned)f2bf(s[5]) << 16);
    o.w = (unsigned)f2bf(s[6]) | ((unsigned)f2bf(s[7]) << 16);
    ((uint4*)P2t)[i] = o;
}

// ---- gemm3: G = x @ P2, no split-K, tile 128x64, f32 direct out ----
// M=4096, N=1024, K=1024. 8 waves (2x4), per-wave 64x16, acc[4].
__global__ __launch_bounds__(512) void gemm3_direct(const u16* __restrict__ A,
                                                    const u16* __restrict__ Bt,
                                                    float* __restrict__ C) {
    __shared__ u16 sA[2][128 * 32];
    __shared__ u16 sB[2][64 * 32];

    const int t = threadIdx.x;
    const int lane = t & 63;
    const int w = t >> 6;
    const int wr = w >> 2, wc = w & 3;
    const int l15 = lane & 15, l4 = lane >> 4;
    const int row0 = blockIdx.y * 128, col0 = blockIdx.x * 64;

    f32x4 acc[4];
#pragma unroll
    for (int m = 0; m < 4; ++m) acc[m] = (f32x4){0.f, 0.f, 0.f, 0.f};

    const bool doB = t < 256;
    const u16* Abase = A  + (size_t)(row0 + (t >> 2)) * 1024 + (t & 3) * 8;
    const u16* Bbase = Bt + (size_t)(col0 + ((t & 255) >> 2)) * 1024 + (t & 3) * 8;

    GLDS16(Abase, &sA[0][t * 8]);
    if (doB) GLDS16(Bbase, &sB[0][(t & 255) * 8]);
    asm volatile("s_waitcnt vmcnt(0)" ::: "memory");
    __builtin_amdgcn_s_barrier();

    int cur = 0;
    for (int kt = 0; kt < 32; ++kt) {
        if (kt + 1 < 32) {
            GLDS16(Abase + (kt + 1) * 32, &sA[cur ^ 1][t * 8]);
            if (doB) GLDS16(Bbase + (kt + 1) * 32, &sB[cur ^ 1][(t & 255) * 8]);
        }

        bf16x8 af[4], bfr;
#pragma unroll
        for (int m = 0; m < 4; ++m)
            af[m] = *(const bf16x8*)&sA[cur][(wr * 64 + m * 16 + l15) * 32 + l4 * 8];
        bfr = *(const bf16x8*)&sB[cur][(wc * 16 + l15) * 32 + l4 * 8];
#pragma unroll
        for (int m = 0; m < 4; ++m)
            acc[m] = __builtin_amdgcn_mfma_f32_16x16x32_bf16(af[m], bfr, acc[m], 0, 0, 0);

        asm volatile("s_waitcnt vmcnt(0)" ::: "memory");
        __builtin_amdgcn_s_barrier();
        cur ^= 1;
    }

#pragma unroll
    for (int m = 0; m < 4; ++m) {
        int r = row0 + wr * 64 + m * 16 + l4 * 4;
        int c = col0 + wc * 16 + l15;
#pragma unroll
        for (int j = 0; j < 4; ++j)
            C[(size_t)(r + j) * 1024 + c] = acc[m][j];
    }
}

// dims: x(4096,1024)  V0(1024,2048) V1(2048,2048) V2(2048,1024)
// out = x @ ((V0@V1)@V2):
//   P1  = V0@V1          (1024x2048 bf16), split-K 4x512 + reduce
//   P2t = V2^T @ P1^T    (1024x1024 bf16), split-K 8x256 + reduce
//   G   = x @ P2         (4096x1024 f32 -> d_out), full-K direct
// d_in order: x, V0, W0, V1, W1, V2, W2
extern "C" void kernel_launch(void* const* d_in, const int* in_sizes, int n_in,
                              void* d_out, int out_size, void* d_ws, size_t ws_size,
                              hipStream_t stream) {
    const float* x  = (const float*)d_in[0];
    const float* V0 = (const float*)d_in[1];
    const float* V1 = (const float*)d_in[3];
    const float* V2 = (const float*)d_in[5];

    char* ws = (char*)d_ws;
    u16* xb   = (u16*)(ws);                          // 8 MB  (4096x1024)
    u16* V0b  = (u16*)(ws + ((size_t)8 << 20));      // 4 MB  (1024x2048)
    u16* V1t  = (u16*)(ws + ((size_t)12 << 20));     // 8 MB  (2048x2048 = V1^T)
    u16* V2t  = (u16*)(ws + ((size_t)20 << 20));     // 4 MB  (1024x2048 = V2^T)
    u16* P1   = (u16*)(ws + ((size_t)24 << 20));     // 4 MB  (1024x2048)
    u16* P2t  = (u16*)(ws + ((size_t)28 << 20));     // 2 MB  (1024x1024)
    u16* part = (u16*)(ws + ((size_t)30 << 20));     // 16 MB max (split-K partials)

    // 1. prep: V0 convert + V1/V2 transpose
    prep<<<2560, 256, 0, stream>>>(V0, V0b, V1, V1t, V2, V2t);

    // 2. P1 partials = V0 @ V1 : split-K 4x512
    gemm_bt<<<dim3(16, 8, 4), 512, 0, stream>>>(V0b, V1t, part, 1024, 2048, 2048, 512);

    // 3. reduce P1 + convert x
    reduce1_xconv<<<3072, 256, 0, stream>>>(part, P1, x, xb);

    // 4. P2t partials = V2^T @ P1^T : split-K 8x256
    gemm_bt<<<dim3(8, 8, 8), 512, 0, stream>>>(V2t, P1, part, 1024, 1024, 2048, 256);

    // 5. reduce P2t
    reduce2<<<512, 256, 0, stream>>>(part, P2t);

    // 6. G = x @ P2 -> d_out (f32), no split-K
    gemm3_direct<<<dim3(16, 32), 512, 0, stream>>>(xb, P2t, (float*)d_out);
}

// Round 11
// 75.003 us; speedup vs baseline: 7.6555x; 1.0063x over previous
//
#include <hip/hip_runtime.h>
#include <hip/hip_bf16.h>

typedef unsigned short u16;
typedef __bf16 bf16x8 __attribute__((ext_vector_type(8)));
typedef float f32x4 __attribute__((ext_vector_type(4)));

__device__ __forceinline__ u16 f2bf(float f) {
    unsigned u = __builtin_bit_cast(unsigned, f);
    unsigned r = (u + 0x7fffu + ((u >> 16) & 1u)) >> 16;
    return (u16)r;
}

#define GLDS16(g, l)                                                      \
    __builtin_amdgcn_global_load_lds(                                     \
        (const __attribute__((address_space(1))) void*)(g),               \
        (__attribute__((address_space(3))) void*)(l), 16, 0, 0)

#define VMW(n) asm volatile("s_waitcnt vmcnt(" #n ")" ::: "memory")
#define CBAR() do { __builtin_amdgcn_s_barrier(); asm volatile("" ::: "memory"); } while (0)

// ---- prep: convert V0 -> bf16; transpose+convert V1 -> V1t, V2 -> V2t ----
__global__ __launch_bounds__(256) void prep(const float* __restrict__ V0,
                                            u16* __restrict__ V0b,
                                            const float* __restrict__ V1,
                                            u16* __restrict__ V1t,
                                            const float* __restrict__ V2,
                                            u16* __restrict__ V2t) {
    __shared__ float tile[64][65];
    const int b = blockIdx.x, t = threadIdx.x;
    if (b < 1024) {
        int i0 = b * 512 + t;
#pragma unroll
        for (int p = 0; p < 2; ++p) {
            int j = i0 + p * 256;
            float4 v = ((const float4*)V0)[j];
            ushort4 o; o.x = f2bf(v.x); o.y = f2bf(v.y); o.z = f2bf(v.z); o.w = f2bf(v.w);
            ((ushort4*)V0b)[j] = o;
        }
        return;
    }
    const int b2 = b - 1024;
    const float* src; u16* dst; int C, rt, ct;
    if (b2 < 1024) { src = V1; dst = V1t; C = 2048; rt = b2 >> 5; ct = b2 & 31; }
    else { int b3 = b2 - 1024; src = V2; dst = V2t; C = 1024; rt = b3 >> 4; ct = b3 & 15; }
    const int r0 = rt * 64, c0 = ct * 64;
    const int trow = t >> 4;
    const int tc4 = t & 15;

#pragma unroll
    for (int p = 0; p < 4; ++p) {
        int r = p * 16 + trow;
        float4 v = *(const float4*)&src[(size_t)(r0 + r) * C + c0 + tc4 * 4];
        tile[r][tc4 * 4 + 0] = v.x; tile[r][tc4 * 4 + 1] = v.y;
        tile[r][tc4 * 4 + 2] = v.z; tile[r][tc4 * 4 + 3] = v.w;
    }
    __syncthreads();
#pragma unroll
    for (int p = 0; p < 4; ++p) {
        int c = p * 16 + trow;
        int rr = tc4 * 4;
        ushort4 o;
        o.x = f2bf(tile[rr + 0][c]); o.y = f2bf(tile[rr + 1][c]);
        o.z = f2bf(tile[rr + 2][c]); o.w = f2bf(tile[rr + 3][c]);
        *(ushort4*)&dst[(size_t)(c0 + c) * 2048 + r0 + rr] = o;
    }
}

// ---------------- bf16 GEMM: Cpart(z) = A(M x Kc slice) * Bt(N x Kc slice)^T --
// 128x128 tile, BK=32, 8 waves (2x4), 4-deep LDS pipeline, counted vmcnt,
// k-chunk XOR swizzle (pre-swizzled global source + XOR'd ds_read -> 2-way banks).
__global__ __launch_bounds__(512) void gemm_bt(const u16* __restrict__ A,
                                               const u16* __restrict__ Bt,
                                               u16* __restrict__ Cpart,
                                               int M, int N, int Ktot, int Kc) {
    __shared__ u16 sA[4][128 * 32];
    __shared__ u16 sB[4][128 * 32];

    const int t = threadIdx.x;
    const int lane = t & 63;
    const int w = t >> 6;
    const int wr = w >> 2, wc = w & 3;
    const int l15 = lane & 15, l4 = lane >> 4;
    const int xk = l4 ^ ((l15 >> 1) & 3);          // swizzled k-chunk for reads
    const int row0 = blockIdx.y * 128, col0 = blockIdx.x * 128;
    const int kbase = blockIdx.z * Kc;

    f32x4 acc[4][2] = {};

    // staging: granule t <- global (row = t>>2, kc = (t&3) ^ ((t>>3)&3))
    const int sr = t >> 2;
    const int skc = (t & 3) ^ ((t >> 3) & 3);
    const u16* Ab = A  + (size_t)(row0 + sr) * Ktot + kbase + skc * 8;
    const u16* Bb = Bt + (size_t)(col0 + sr) * Ktot + kbase + skc * 8;

    // prologue: stage tiles 0..2
#pragma unroll
    for (int p = 0; p < 3; ++p) {
        GLDS16(Ab + p * 32, &sA[p][t * 8]);
        GLDS16(Bb + p * 32, &sB[p][t * 8]);
    }

    auto compute = [&](int kk) {
        const u16* bufA = sA[kk & 3];
        const u16* bufB = sB[kk & 3];
        bf16x8 af[4], bfr[2];
#pragma unroll
        for (int m = 0; m < 4; ++m)
            af[m] = *(const bf16x8*)&bufA[(wr * 64 + m * 16 + l15) * 32 + xk * 8];
#pragma unroll
        for (int n = 0; n < 2; ++n)
            bfr[n] = *(const bf16x8*)&bufB[(wc * 32 + n * 16 + l15) * 32 + xk * 8];
#pragma unroll
        for (int m = 0; m < 4; ++m)
#pragma unroll
            for (int n = 0; n < 2; ++n)
                acc[m][n] = __builtin_amdgcn_mfma_f32_16x16x32_bf16(af[m], bfr[n], acc[m][n], 0, 0, 0);
    };

    const int nK = Kc >> 5;   // >= 4 for all launches
    int k = 0;
    for (; k + 3 < nK; ++k) {
        VMW(4);                // tile k's 2 loads retired (issued 3 iters ago)
        CBAR();
        GLDS16(Ab + (size_t)(k + 3) * 32, &sA[(k + 3) & 3][t * 8]);
        GLDS16(Bb + (size_t)(k + 3) * 32, &sB[(k + 3) & 3][t * 8]);
        compute(k);
    }
    VMW(4); CBAR(); compute(nK - 3);
    VMW(2); CBAR(); compute(nK - 2);
    VMW(0); CBAR(); compute(nK - 1);

    // epilogue: D row = (lane>>4)*4 + j, col = lane&15  [verified layout]
    const size_t zoff = (size_t)blockIdx.z * M * N;
#pragma unroll
    for (int m = 0; m < 4; ++m)
#pragma unroll
        for (int n = 0; n < 2; ++n) {
            int r = row0 + wr * 64 + m * 16 + l4 * 4;
            int c = col0 + wc * 32 + n * 16 + l15;
#pragma unroll
            for (int j = 0; j < 4; ++j)
                Cpart[zoff + (size_t)(r + j) * N + c] = f2bf(acc[m][n][j]);
        }
}

// ---- reduce1 (4 partials -> P1 bf16) + x f32->bf16 convert, fused ----
__global__ __launch_bounds__(256) void reduce1_xconv(const u16* __restrict__ part,
                                                     u16* __restrict__ P1,
                                                     const float* __restrict__ x,
                                                     u16* __restrict__ xb) {
    const int b = blockIdx.x, t = threadIdx.x;
    if (b < 1024) {
        const int mn = 1024 * 2048;
        int i = b * 256 + t;
        float s[8] = {0, 0, 0, 0, 0, 0, 0, 0};
#pragma unroll
        for (int z = 0; z < 4; ++z) {
            uint4 v = ((const uint4*)(part + (size_t)z * mn))[i];
            unsigned a0 = v.x, a1 = v.y, a2 = v.z, a3 = v.w;
            s[0] += __builtin_bit_cast(float, a0 << 16);
            s[1] += __builtin_bit_cast(float, a0 & 0xffff0000u);
            s[2] += __builtin_bit_cast(float, a1 << 16);
            s[3] += __builtin_bit_cast(float, a1 & 0xffff0000u);
            s[4] += __builtin_bit_cast(float, a2 << 16);
            s[5] += __builtin_bit_cast(float, a2 & 0xffff0000u);
            s[6] += __builtin_bit_cast(float, a3 << 16);
            s[7] += __builtin_bit_cast(float, a3 & 0xffff0000u);
        }
        uint4 o;
        o.x = (unsigned)f2bf(s[0]) | ((unsigned)f2bf(s[1]) << 16);
        o.y = (unsigned)f2bf(s[2]) | ((unsigned)f2bf(s[3]) << 16);
        o.z = (unsigned)f2bf(s[4]) | ((unsigned)f2bf(s[5]) << 16);
        o.w = (unsigned)f2bf(s[6]) | ((unsigned)f2bf(s[7]) << 16);
        ((uint4*)P1)[i] = o;
        return;
    }
    int i0 = (b - 1024) * 512 + t;
#pragma unroll
    for (int p = 0; p < 2; ++p) {
        int j = i0 + p * 256;
        float4 v = ((const float4*)x)[j];
        ushort4 o; o.x = f2bf(v.x); o.y = f2bf(v.y); o.z = f2bf(v.z); o.w = f2bf(v.w);
        ((ushort4*)xb)[j] = o;
    }
}

// ---- reduce2: sum 8 bf16 partials -> P2t bf16 ----
__global__ __launch_bounds__(256) void reduce2(const u16* __restrict__ part,
                                               u16* __restrict__ P2t) {
    const int mn = 1024 * 1024;
    int i = blockIdx.x * 256 + threadIdx.x;
    float s[8] = {0, 0, 0, 0, 0, 0, 0, 0};
#pragma unroll
    for (int z = 0; z < 8; ++z) {
        uint4 v = ((const uint4*)(part + (size_t)z * mn))[i];
        unsigned a0 = v.x, a1 = v.y, a2 = v.z, a3 = v.w;
        s[0] += __builtin_bit_cast(float, a0 << 16);
        s[1] += __builtin_bit_cast(float, a0 & 0xffff0000u);
        s[2] += __builtin_bit_cast(float, a1 << 16);
        s[3] += __builtin_bit_cast(float, a1 & 0xffff0000u);
        s[4] += __builtin_bit_cast(float, a2 << 16);
        s[5] += __builtin_bit_cast(float, a2 & 0xffff0000u);
        s[6] += __builtin_bit_cast(float, a3 << 16);
        s[7] += __builtin_bit_cast(float, a3 & 0xffff0000u);
    }
    uint4 o;
    o.x = (unsigned)f2bf(s[0]) | ((unsigned)f2bf(s[1]) << 16);
    o.y = (unsigned)f2bf(s[2]) | ((unsigned)f2bf(s[3]) << 16);
    o.z = (unsigned)f2bf(s[4]) | ((unsigned)f2bf(s[5]) << 16);
    o.w = (unsigned)f2bf(s[6]) | ((unsigned)f2bf(s[7]) << 16);
    ((uint4*)P2t)[i] = o;
}

// ---- gemm3: G = x @ P2, no split-K, tile 128x64, f32 direct out ----
// A staged by all 512 threads (1 seg), B by t<256 (1 seg) -> wave-uniform
// dual vmcnt counts (B-waves 2 loads/iter, A-only waves 1 load/iter).
__global__ __launch_bounds__(512) void gemm3_direct(const u16* __restrict__ A,
                                                    const u16* __restrict__ Bt,
                                                    float* __restrict__ C) {
    __shared__ u16 sA[4][128 * 32];
    __shared__ u16 sB[4][64 * 32];

    const int t = threadIdx.x;
    const int lane = t & 63;
    const int w = t >> 6;
    const int wr = w >> 2, wc = w & 3;
    const int l15 = lane & 15, l4 = lane >> 4;
    const int xk = l4 ^ ((l15 >> 1) & 3);
    const int row0 = blockIdx.y * 128, col0 = blockIdx.x * 64;

    f32x4 acc[4];
#pragma unroll
    for (int m = 0; m < 4; ++m) acc[m] = (f32x4){0.f, 0.f, 0.f, 0.f};

    const bool doB = t < 256;
    const int skc = (t & 3) ^ ((t >> 3) & 3);
    const u16* Abase = A  + (size_t)(row0 + (t >> 2)) * 1024 + skc * 8;
    const u16* Bbase = Bt + (size_t)(col0 + ((t & 255) >> 2)) * 1024 + skc * 8;

#pragma unroll
    for (int p = 0; p < 3; ++p) {
        GLDS16(Abase + p * 32, &sA[p][t * 8]);
        if (doB) GLDS16(Bbase + p * 32, &sB[p][(t & 255) * 8]);
    }

    auto compute = [&](int kk) {
        const u16* bufA = sA[kk & 3];
        const u16* bufB = sB[kk & 3];
        bf16x8 af[4], bfr;
#pragma unroll
        for (int m = 0; m < 4; ++m)
            af[m] = *(const bf16x8*)&bufA[(wr * 64 + m * 16 + l15) * 32 + xk * 8];
        bfr = *(const bf16x8*)&bufB[(wc * 16 + l15) * 32 + xk * 8];
#pragma unroll
        for (int m = 0; m < 4; ++m)
            acc[m] = __builtin_amdgcn_mfma_f32_16x16x32_bf16(af[m], bfr, acc[m], 0, 0, 0);
    };

    const int nK = 32;
    int k = 0;
    for (; k + 3 < nK; ++k) {
        if (doB) { VMW(4); } else { VMW(2); }
        CBAR();
        GLDS16(Abase + (size_t)(k + 3) * 32, &sA[(k + 3) & 3][t * 8]);
        if (doB) GLDS16(Bbase + (size_t)(k + 3) * 32, &sB[(k + 3) & 3][(t & 255) * 8]);
        compute(k);
    }
    if (doB) { VMW(4); } else { VMW(2); }
    CBAR(); compute(nK - 3);
    if (doB) { VMW(2); } else { VMW(1); }
    CBAR(); compute(nK - 2);
    VMW(0);
    CBAR(); compute(nK - 1);

#pragma unroll
    for (int m = 0; m < 4; ++m) {
        int r = row0 + wr * 64 + m * 16 + l4 * 4;
        int c = col0 + wc * 16 + l15;
#pragma unroll
        for (int j = 0; j < 4; ++j)
            C[(size_t)(r + j) * 1024 + c] = acc[m][j];
    }
}

// dims: x(4096,1024)  V0(1024,2048) V1(2048,2048) V2(2048,1024)
// out = x @ ((V0@V1)@V2)
// d_in order: x, V0, W0, V1, W1, V2, W2
extern "C" void kernel_launch(void* const* d_in, const int* in_sizes, int n_in,
                              void* d_out, int out_size, void* d_ws, size_t ws_size,
                              hipStream_t stream) {
    const float* x  = (const float*)d_in[0];
    const float* V0 = (const float*)d_in[1];
    const float* V1 = (const float*)d_in[3];
    const float* V2 = (const float*)d_in[5];

    char* ws = (char*)d_ws;
    u16* xb   = (u16*)(ws);                          // 8 MB  (4096x1024)
    u16* V0b  = (u16*)(ws + ((size_t)8 << 20));      // 4 MB  (1024x2048)
    u16* V1t  = (u16*)(ws + ((size_t)12 << 20));     // 8 MB  (2048x2048 = V1^T)
    u16* V2t  = (u16*)(ws + ((size_t)20 << 20));     // 4 MB  (1024x2048 = V2^T)
    u16* P1   = (u16*)(ws + ((size_t)24 << 20));     // 4 MB  (1024x2048)
    u16* P2t  = (u16*)(ws + ((size_t)28 << 20));     // 2 MB  (1024x1024)
    u16* part = (u16*)(ws + ((size_t)30 << 20));     // 16 MB max (split-K partials)

    // 1. prep: V0 convert + V1/V2 transpose
    prep<<<2560, 256, 0, stream>>>(V0, V0b, V1, V1t, V2, V2t);

    // 2. P1 partials = V0 @ V1 : split-K 4x512
    gemm_bt<<<dim3(16, 8, 4), 512, 0, stream>>>(V0b, V1t, part, 1024, 2048, 2048, 512);

    // 3. reduce P1 + convert x
    reduce1_xconv<<<3072, 256, 0, stream>>>(part, P1, x, xb);

    // 4. P2t partials = V2^T @ P1^T : split-K 8x256
    gemm_bt<<<dim3(8, 8, 8), 512, 0, stream>>>(V2t, P1, part, 1024, 1024, 2048, 256);

    // 5. reduce P2t
    reduce2<<<512, 256, 0, stream>>>(part, P2t);

    // 6. G = x @ P2 -> d_out (f32), no split-K
    gemm3_direct<<<dim3(16, 32), 512, 0, stream>>>(xb, P2t, (float*)d_out);
}

// Round 12
// 74.626 us; speedup vs baseline: 7.6942x; 1.0051x over previous
//
#include <hip/hip_runtime.h>
#include <hip/hip_bf16.h>

typedef unsigned short u16;
typedef __bf16 bf16x8 __attribute__((ext_vector_type(8)));
typedef float f32x4 __attribute__((ext_vector_type(4)));

__device__ __forceinline__ u16 f2bf(float f) {
    unsigned u = __builtin_bit_cast(unsigned, f);
    unsigned r = (u + 0x7fffu + ((u >> 16) & 1u)) >> 16;
    return (u16)r;
}

#define GLDS16(g, l)                                                      \
    __builtin_amdgcn_global_load_lds(                                     \
        (const __attribute__((address_space(1))) void*)(g),               \
        (__attribute__((address_space(3))) void*)(l), 16, 0, 0)

#define VMW(n) asm volatile("s_waitcnt vmcnt(" #n ")" ::: "memory")
#define CBAR() do { __builtin_amdgcn_s_barrier(); asm volatile("" ::: "memory"); } while (0)

// ---- prep: convert V0 -> bf16; transpose+convert V1 -> V1t, V2 -> V2t ----
__global__ __launch_bounds__(256) void prep(const float* __restrict__ V0,
                                            u16* __restrict__ V0b,
                                            const float* __restrict__ V1,
                                            u16* __restrict__ V1t,
                                            const float* __restrict__ V2,
                                            u16* __restrict__ V2t) {
    __shared__ float tile[64][65];
    const int b = blockIdx.x, t = threadIdx.x;
    if (b < 1024) {
        int i0 = b * 512 + t;
#pragma unroll
        for (int p = 0; p < 2; ++p) {
            int j = i0 + p * 256;
            float4 v = ((const float4*)V0)[j];
            ushort4 o; o.x = f2bf(v.x); o.y = f2bf(v.y); o.z = f2bf(v.z); o.w = f2bf(v.w);
            ((ushort4*)V0b)[j] = o;
        }
        return;
    }
    const int b2 = b - 1024;
    const float* src; u16* dst; int C, rt, ct;
    if (b2 < 1024) { src = V1; dst = V1t; C = 2048; rt = b2 >> 5; ct = b2 & 31; }
    else { int b3 = b2 - 1024; src = V2; dst = V2t; C = 1024; rt = b3 >> 4; ct = b3 & 15; }
    const int r0 = rt * 64, c0 = ct * 64;
    const int trow = t >> 4;
    const int tc4 = t & 15;

#pragma unroll
    for (int p = 0; p < 4; ++p) {
        int r = p * 16 + trow;
        float4 v = *(const float4*)&src[(size_t)(r0 + r) * C + c0 + tc4 * 4];
        tile[r][tc4 * 4 + 0] = v.x; tile[r][tc4 * 4 + 1] = v.y;
        tile[r][tc4 * 4 + 2] = v.z; tile[r][tc4 * 4 + 3] = v.w;
    }
    __syncthreads();
#pragma unroll
    for (int p = 0; p < 4; ++p) {
        int c = p * 16 + trow;
        int rr = tc4 * 4;
        ushort4 o;
        o.x = f2bf(tile[rr + 0][c]); o.y = f2bf(tile[rr + 1][c]);
        o.z = f2bf(tile[rr + 2][c]); o.w = f2bf(tile[rr + 3][c]);
        *(ushort4*)&dst[(size_t)(c0 + c) * 2048 + r0 + rr] = o;
    }
}

// ---------------- bf16 GEMM: Cpart(z) = A(M x Kc slice) * Bt(N x Kc slice)^T --
// 128x128 tile, BK=32, 8 waves (2x4), 4-deep LDS pipeline, counted vmcnt,
// k-chunk XOR swizzle. 1D grid with XCD-locality decode:
//   by = L & 7 (A-panel cluster per XCD), bx = (L>>3) & (2^BXB-1), z = L >> (3+BXB).
template <int BXB>
__global__ __launch_bounds__(512) void gemm_bt(const u16* __restrict__ A,
                                               const u16* __restrict__ Bt,
                                               u16* __restrict__ Cpart,
                                               int M, int N, int Ktot, int Kc) {
    __shared__ u16 sA[4][128 * 32];
    __shared__ u16 sB[4][128 * 32];

    const int L = blockIdx.x;
    const int by = L & 7;
    const int bx = (L >> 3) & ((1 << BXB) - 1);
    const int bz = L >> (3 + BXB);

    const int t = threadIdx.x;
    const int lane = t & 63;
    const int w = t >> 6;
    const int wr = w >> 2, wc = w & 3;
    const int l15 = lane & 15, l4 = lane >> 4;
    const int xk = l4 ^ ((l15 >> 1) & 3);          // swizzled k-chunk for reads
    const int row0 = by * 128, col0 = bx * 128;
    const int kbase = bz * Kc;

    f32x4 acc[4][2] = {};

    const int sr = t >> 2;
    const int skc = (t & 3) ^ ((t >> 3) & 3);
    const u16* Ab = A  + (size_t)(row0 + sr) * Ktot + kbase + skc * 8;
    const u16* Bb = Bt + (size_t)(col0 + sr) * Ktot + kbase + skc * 8;

#pragma unroll
    for (int p = 0; p < 3; ++p) {
        GLDS16(Ab + p * 32, &sA[p][t * 8]);
        GLDS16(Bb + p * 32, &sB[p][t * 8]);
    }

    auto compute = [&](int kk) {
        const u16* bufA = sA[kk & 3];
        const u16* bufB = sB[kk & 3];
        bf16x8 af[4], bfr[2];
#pragma unroll
        for (int m = 0; m < 4; ++m)
            af[m] = *(const bf16x8*)&bufA[(wr * 64 + m * 16 + l15) * 32 + xk * 8];
#pragma unroll
        for (int n = 0; n < 2; ++n)
            bfr[n] = *(const bf16x8*)&bufB[(wc * 32 + n * 16 + l15) * 32 + xk * 8];
#pragma unroll
        for (int m = 0; m < 4; ++m)
#pragma unroll
            for (int n = 0; n < 2; ++n)
                acc[m][n] = __builtin_amdgcn_mfma_f32_16x16x32_bf16(af[m], bfr[n], acc[m][n], 0, 0, 0);
    };

    const int nK = Kc >> 5;   // >= 8 for all launches
    int k = 0;
    for (; k + 3 < nK; ++k) {
        VMW(4);                // tile k's 2 loads retired (issued 3 iters ago)
        CBAR();
        GLDS16(Ab + (size_t)(k + 3) * 32, &sA[(k + 3) & 3][t * 8]);
        GLDS16(Bb + (size_t)(k + 3) * 32, &sB[(k + 3) & 3][t * 8]);
        compute(k);
    }
    VMW(4); CBAR(); compute(nK - 3);
    VMW(2); CBAR(); compute(nK - 2);
    VMW(0); CBAR(); compute(nK - 1);

    // epilogue: D row = (lane>>4)*4 + j, col = lane&15  [verified layout]
    const size_t zoff = (size_t)bz * M * N;
#pragma unroll
    for (int m = 0; m < 4; ++m)
#pragma unroll
        for (int n = 0; n < 2; ++n) {
            int r = row0 + wr * 64 + m * 16 + l4 * 4;
            int c = col0 + wc * 32 + n * 16 + l15;
#pragma unroll
            for (int j = 0; j < 4; ++j)
                Cpart[zoff + (size_t)(r + j) * N + c] = f2bf(acc[m][n][j]);
        }
}

// ---- reduce1 (4 partials -> P1 bf16) + x f32->bf16 convert, fused ----
__global__ __launch_bounds__(256) void reduce1_xconv(const u16* __restrict__ part,
                                                     u16* __restrict__ P1,
                                                     const float* __restrict__ x,
                                                     u16* __restrict__ xb) {
    const int b = blockIdx.x, t = threadIdx.x;
    if (b < 1024) {
        const int mn = 1024 * 2048;
        int i = b * 256 + t;
        float s[8] = {0, 0, 0, 0, 0, 0, 0, 0};
#pragma unroll
        for (int z = 0; z < 4; ++z) {
            uint4 v = ((const uint4*)(part + (size_t)z * mn))[i];
            unsigned a0 = v.x, a1 = v.y, a2 = v.z, a3 = v.w;
            s[0] += __builtin_bit_cast(float, a0 << 16);
            s[1] += __builtin_bit_cast(float, a0 & 0xffff0000u);
            s[2] += __builtin_bit_cast(float, a1 << 16);
            s[3] += __builtin_bit_cast(float, a1 & 0xffff0000u);
            s[4] += __builtin_bit_cast(float, a2 << 16);
            s[5] += __builtin_bit_cast(float, a2 & 0xffff0000u);
            s[6] += __builtin_bit_cast(float, a3 << 16);
            s[7] += __builtin_bit_cast(float, a3 & 0xffff0000u);
        }
        uint4 o;
        o.x = (unsigned)f2bf(s[0]) | ((unsigned)f2bf(s[1]) << 16);
        o.y = (unsigned)f2bf(s[2]) | ((unsigned)f2bf(s[3]) << 16);
        o.z = (unsigned)f2bf(s[4]) | ((unsigned)f2bf(s[5]) << 16);
        o.w = (unsigned)f2bf(s[6]) | ((unsigned)f2bf(s[7]) << 16);
        ((uint4*)P1)[i] = o;
        return;
    }
    int i0 = (b - 1024) * 512 + t;
#pragma unroll
    for (int p = 0; p < 2; ++p) {
        int j = i0 + p * 256;
        float4 v = ((const float4*)x)[j];
        ushort4 o; o.x = f2bf(v.x); o.y = f2bf(v.y); o.z = f2bf(v.z); o.w = f2bf(v.w);
        ((ushort4*)xb)[j] = o;
    }
}

// ---- reduce2: sum 8 bf16 partials -> P2t bf16 ----
__global__ __launch_bounds__(256) void reduce2(const u16* __restrict__ part,
                                               u16* __restrict__ P2t) {
    const int mn = 1024 * 1024;
    int i = blockIdx.x * 256 + threadIdx.x;
    float s[8] = {0, 0, 0, 0, 0, 0, 0, 0};
#pragma unroll
    for (int z = 0; z < 8; ++z) {
        uint4 v = ((const uint4*)(part + (size_t)z * mn))[i];
        unsigned a0 = v.x, a1 = v.y, a2 = v.z, a3 = v.w;
        s[0] += __builtin_bit_cast(float, a0 << 16);
        s[1] += __builtin_bit_cast(float, a0 & 0xffff0000u);
        s[2] += __builtin_bit_cast(float, a1 << 16);
        s[3] += __builtin_bit_cast(float, a1 & 0xffff0000u);
        s[4] += __builtin_bit_cast(float, a2 << 16);
        s[5] += __builtin_bit_cast(float, a2 & 0xffff0000u);
        s[6] += __builtin_bit_cast(float, a3 << 16);
        s[7] += __builtin_bit_cast(float, a3 & 0xffff0000u);
    }
    uint4 o;
    o.x = (unsigned)f2bf(s[0]) | ((unsigned)f2bf(s[1]) << 16);
    o.y = (unsigned)f2bf(s[2]) | ((unsigned)f2bf(s[3]) << 16);
    o.z = (unsigned)f2bf(s[4]) | ((unsigned)f2bf(s[5]) << 16);
    o.w = (unsigned)f2bf(s[6]) | ((unsigned)f2bf(s[7]) << 16);
    ((uint4*)P2t)[i] = o;
}

// ---- gemm3: G = x @ P2, no split-K, tile 128x64, f32 direct out ----
// 1D grid 512 with XCD-locality decode: by = (L&7) + 8*(L>>7), bx = (L>>3)&15.
// Per XCD: 4 A-panels (1 MB) + all of P2t (2 MB) stay L2-resident.
__global__ __launch_bounds__(512) void gemm3_direct(const u16* __restrict__ A,
                                                    const u16* __restrict__ Bt,
                                                    float* __restrict__ C) {
    __shared__ u16 sA[4][128 * 32];
    __shared__ u16 sB[4][64 * 32];

    const int L = blockIdx.x;
    const int bx = (L >> 3) & 15;
    const int by = (L & 7) + 8 * (L >> 7);

    const int t = threadIdx.x;
    const int lane = t & 63;
    const int w = t >> 6;
    const int wr = w >> 2, wc = w & 3;
    const int l15 = lane & 15, l4 = lane >> 4;
    const int xk = l4 ^ ((l15 >> 1) & 3);
    const int row0 = by * 128, col0 = bx * 64;

    f32x4 acc[4];
#pragma unroll
    for (int m = 0; m < 4; ++m) acc[m] = (f32x4){0.f, 0.f, 0.f, 0.f};

    const bool doB = t < 256;
    const int skc = (t & 3) ^ ((t >> 3) & 3);
    const u16* Abase = A  + (size_t)(row0 + (t >> 2)) * 1024 + skc * 8;
    const u16* Bbase = Bt + (size_t)(col0 + ((t & 255) >> 2)) * 1024 + skc * 8;

#pragma unroll
    for (int p = 0; p < 3; ++p) {
        GLDS16(Abase + p * 32, &sA[p][t * 8]);
        if (doB) GLDS16(Bbase + p * 32, &sB[p][(t & 255) * 8]);
    }

    auto compute = [&](int kk) {
        const u16* bufA = sA[kk & 3];
        const u16* bufB = sB[kk & 3];
        bf16x8 af[4], bfr;
#pragma unroll
        for (int m = 0; m < 4; ++m)
            af[m] = *(const bf16x8*)&bufA[(wr * 64 + m * 16 + l15) * 32 + xk * 8];
        bfr = *(const bf16x8*)&bufB[(wc * 16 + l15) * 32 + xk * 8];
#pragma unroll
        for (int m = 0; m < 4; ++m)
            acc[m] = __builtin_amdgcn_mfma_f32_16x16x32_bf16(af[m], bfr, acc[m], 0, 0, 0);
    };

    const int nK = 32;
    int k = 0;
    for (; k + 3 < nK; ++k) {
        if (doB) { VMW(4); } else { VMW(2); }
        CBAR();
        GLDS16(Abase + (size_t)(k + 3) * 32, &sA[(k + 3) & 3][t * 8]);
        if (doB) GLDS16(Bbase + (size_t)(k + 3) * 32, &sB[(k + 3) & 3][(t & 255) * 8]);
        compute(k);
    }
    if (doB) { VMW(4); } else { VMW(2); }
    CBAR(); compute(nK - 3);
    if (doB) { VMW(2); } else { VMW(1); }
    CBAR(); compute(nK - 2);
    VMW(0);
    CBAR(); compute(nK - 1);

#pragma unroll
    for (int m = 0; m < 4; ++m) {
        int r = row0 + wr * 64 + m * 16 + l4 * 4;
        int c = col0 + wc * 16 + l15;
#pragma unroll
        for (int j = 0; j < 4; ++j)
            C[(size_t)(r + j) * 1024 + c] = acc[m][j];
    }
}

// dims: x(4096,1024)  V0(1024,2048) V1(2048,2048) V2(2048,1024)
// out = x @ ((V0@V1)@V2)
// d_in order: x, V0, W0, V1, W1, V2, W2
extern "C" void kernel_launch(void* const* d_in, const int* in_sizes, int n_in,
                              void* d_out, int out_size, void* d_ws, size_t ws_size,
                              hipStream_t stream) {
    const float* x  = (const float*)d_in[0];
    const float* V0 = (const float*)d_in[1];
    const float* V1 = (const float*)d_in[3];
    const float* V2 = (const float*)d_in[5];

    char* ws = (char*)d_ws;
    u16* xb   = (u16*)(ws);                          // 8 MB  (4096x1024)
    u16* V0b  = (u16*)(ws + ((size_t)8 << 20));      // 4 MB  (1024x2048)
    u16* V1t  = (u16*)(ws + ((size_t)12 << 20));     // 8 MB  (2048x2048 = V1^T)
    u16* V2t  = (u16*)(ws + ((size_t)20 << 20));     // 4 MB  (1024x2048 = V2^T)
    u16* P1   = (u16*)(ws + ((size_t)24 << 20));     // 4 MB  (1024x2048)
    u16* P2t  = (u16*)(ws + ((size_t)28 << 20));     // 2 MB  (1024x1024)
    u16* part = (u16*)(ws + ((size_t)30 << 20));     // 16 MB max (split-K partials)

    // 1. prep: V0 convert + V1/V2 transpose
    prep<<<2560, 256, 0, stream>>>(V0, V0b, V1, V1t, V2, V2t);

    // 2. P1 partials = V0 @ V1 : split-K 4x512  (grid decode: by=L&7, bx 4b, z 2b)
    gemm_bt<4><<<512, 512, 0, stream>>>(V0b, V1t, part, 1024, 2048, 2048, 512);

    // 3. reduce P1 + convert x
    reduce1_xconv<<<3072, 256, 0, stream>>>(part, P1, x, xb);

    // 4. P2t partials = V2^T @ P1^T : split-K 8x256  (by=L&7, bx 3b, z 3b)
    gemm_bt<3><<<512, 512, 0, stream>>>(V2t, P1, part, 1024, 1024, 2048, 256);

    // 5. reduce P2t
    reduce2<<<512, 256, 0, stream>>>(part, P2t);

    // 6. G = x @ P2 -> d_out (f32), no split-K
    gemm3_direct<<<512, 512, 0, stream>>>(xb, P2t, (float*)d_out);
}